// Round 1
// baseline (2576.584 us; speedup 1.0000x reference)
//
#include <hip/hip_runtime.h>

#define B_   128
#define H_   256
#define WI_  256
#define CIN  8
#define COUT 8
#define TH   16   // output rows per block
#define PCH  4    // output rows per chunk (register tile)

__global__ __launch_bounds__(256, 3)
void conv_aconnect_kernel(const float* __restrict__ X,
                          const float* __restrict__ Wt,
                          const float* __restrict__ bias,
                          const float* __restrict__ Werr,
                          const float* __restrict__ Berr,
                          float* __restrict__ out)
{
    __shared__ float wlds[3 * 3 * CIN * COUT];   // 576 floats, per-sample noisy weights
    __shared__ float blds[COUT];

    const int tid   = threadIdx.x;        // 0..255 = column
    const int strip = blockIdx.x;         // 0..15
    const int b     = blockIdx.y;         // 0..127

    // --- per-sample weights / bias into LDS (uniform per block) ---
    {
        const float* werr_b = Werr + (size_t)b * 576;
        for (int i = tid; i < 576; i += 256)
            wlds[i] = Wt[i] * werr_b[i];
        if (tid < COUT)
            blds[tid] = bias[tid] * Berr[(size_t)b * COUT + tid];
    }
    __syncthreads();

    const int w = tid;
    const float* xb = X   + (size_t)b * H_ * WI_ * CIN;
    float*       ob = out + (size_t)b * H_ * WI_ * COUT;

    float bv[COUT];
    #pragma unroll
    for (int c = 0; c < COUT; ++c) bv[c] = blds[c];

    #pragma unroll 1
    for (int ch = 0; ch < TH / PCH; ++ch) {
        const int r0 = strip * TH + ch * PCH;

        float acc[PCH][COUT];
        #pragma unroll
        for (int p = 0; p < PCH; ++p)
            #pragma unroll
            for (int c = 0; c < COUT; ++c) acc[p][c] = bv[c];

        #pragma unroll
        for (int kw = 0; kw < 3; ++kw) {
            const int  col = w + kw - 1;
            const bool cok = ((unsigned)col < (unsigned)WI_);

            // input strip: rows r0-1 .. r0+PCH, 8 channels as two float4
            float4 xs0[PCH + 2], xs1[PCH + 2];
            #pragma unroll
            for (int j = 0; j < PCH + 2; ++j) {
                const int  row = r0 + j - 1;
                const bool rok = ((unsigned)row < (unsigned)H_);
                if (cok && rok) {
                    const float* p4 = xb + ((size_t)row * WI_ + col) * CIN;
                    xs0[j] = *(const float4*)(p4);
                    xs1[j] = *(const float4*)(p4 + 4);
                } else {
                    xs0[j] = make_float4(0.f, 0.f, 0.f, 0.f);
                    xs1[j] = make_float4(0.f, 0.f, 0.f, 0.f);
                }
            }

            #pragma unroll
            for (int kh = 0; kh < 3; ++kh) {
                #pragma unroll
                for (int ci = 0; ci < CIN; ++ci) {
                    const int wbase = ((kh * 3 + kw) * CIN + ci) * COUT;
                    const float4 wv0 = *(const float4*)&wlds[wbase];
                    const float4 wv1 = *(const float4*)&wlds[wbase + 4];
                    #pragma unroll
                    for (int p = 0; p < PCH; ++p) {
                        const float xv = (ci < 4)
                            ? ((const float*)&xs0[p + kh])[ci]
                            : ((const float*)&xs1[p + kh])[ci - 4];
                        acc[p][0] += xv * wv0.x;
                        acc[p][1] += xv * wv0.y;
                        acc[p][2] += xv * wv0.z;
                        acc[p][3] += xv * wv0.w;
                        acc[p][4] += xv * wv1.x;
                        acc[p][5] += xv * wv1.y;
                        acc[p][6] += xv * wv1.z;
                        acc[p][7] += xv * wv1.w;
                    }
                }
            }
        }

        #pragma unroll
        for (int p = 0; p < PCH; ++p) {
            float* po = ob + ((size_t)(r0 + p) * WI_ + w) * COUT;
            *(float4*)(po)     = make_float4(acc[p][0], acc[p][1], acc[p][2], acc[p][3]);
            *(float4*)(po + 4) = make_float4(acc[p][4], acc[p][5], acc[p][6], acc[p][7]);
        }
    }
}

extern "C" void kernel_launch(void* const* d_in, const int* in_sizes, int n_in,
                              void* d_out, int out_size, void* d_ws, size_t ws_size,
                              hipStream_t stream) {
    const float* X    = (const float*)d_in[0];
    const float* Wt   = (const float*)d_in[1];
    const float* bias = (const float*)d_in[2];
    const float* Werr = (const float*)d_in[3];
    const float* Berr = (const float*)d_in[4];
    float* out = (float*)d_out;

    dim3 grid(H_ / TH, B_);
    conv_aconnect_kernel<<<grid, 256, 0, stream>>>(X, Wt, bias, Werr, Berr, out);
}

// Round 2
// 2560.568 us; speedup vs baseline: 1.0063x; 1.0063x over previous
//
#include <hip/hip_runtime.h>

#define B_   128
#define H_   256
#define WI_  256
#define CIN  8
#define COUT 8
#define TH   16   // output rows per block
#define PCH  4    // output rows per register chunk

__global__ __launch_bounds__(256, 3)
void conv_aconnect_kernel(const float* __restrict__ X,
                          const float* __restrict__ Wt,
                          const float* __restrict__ bias,
                          const float* __restrict__ Werr,
                          const float* __restrict__ Berr,
                          float* __restrict__ out)
{
    __shared__ float wlds[3 * 3 * CIN * COUT];   // per-sample noisy weights
    __shared__ float blds[COUT];

    const int tid   = threadIdx.x;        // 0..255 = output column
    const int strip = blockIdx.x;         // 0..15
    const int b     = blockIdx.y;         // 0..127

    // per-sample weights / bias into LDS
    {
        const float* werr_b = Werr + (size_t)b * 576;
        for (int i = tid; i < 576; i += 256)
            wlds[i] = Wt[i] * werr_b[i];
        if (tid < COUT)
            blds[tid] = bias[tid] * Berr[(size_t)b * COUT + tid];
    }
    __syncthreads();

    const int w = tid;
    const float* xb = X   + (size_t)b * H_ * WI_ * CIN;
    float*       ob = out + (size_t)b * H_ * WI_ * COUT;

    float bv[COUT];
    #pragma unroll
    for (int c = 0; c < COUT; ++c) bv[c] = blds[c];

    #pragma unroll 1
    for (int ch = 0; ch < TH / PCH; ++ch) {
        const int r0 = strip * TH + ch * PCH;

        float acc[PCH][COUT];
        #pragma unroll
        for (int p = 0; p < PCH; ++p)
            #pragma unroll
            for (int c = 0; c < COUT; ++c) acc[p][c] = bv[c];

        #pragma unroll
        for (int kw = 0; kw < 3; ++kw) {
            const int  col = w + kw - 1;
            const bool cok = ((unsigned)col < (unsigned)WI_);

            // input strip rows r0-1 .. r0+PCH, 8 channels each, as plain
            // scalars (NO pointer casts into the array -> stays in VGPRs)
            float xr[PCH + 2][CIN];
            #pragma unroll
            for (int j = 0; j < PCH + 2; ++j) {
                const int  row = r0 + j - 1;
                float4 a = make_float4(0.f, 0.f, 0.f, 0.f);
                float4 c = make_float4(0.f, 0.f, 0.f, 0.f);
                if (cok && ((unsigned)row < (unsigned)H_)) {
                    const float* p4 = xb + ((size_t)row * WI_ + col) * CIN;
                    a = *(const float4*)(p4);
                    c = *(const float4*)(p4 + 4);
                }
                xr[j][0] = a.x; xr[j][1] = a.y; xr[j][2] = a.z; xr[j][3] = a.w;
                xr[j][4] = c.x; xr[j][5] = c.y; xr[j][6] = c.z; xr[j][7] = c.w;
            }

            #pragma unroll
            for (int kh = 0; kh < 3; ++kh) {
                #pragma unroll
                for (int ci = 0; ci < CIN; ++ci) {
                    const int wbase = ((kh * 3 + kw) * CIN + ci) * COUT;
                    const float4 wv0 = *(const float4*)&wlds[wbase];
                    const float4 wv1 = *(const float4*)&wlds[wbase + 4];
                    #pragma unroll
                    for (int p = 0; p < PCH; ++p) {
                        const float xv = xr[p + kh][ci];   // constant idx after unroll
                        acc[p][0] += xv * wv0.x;
                        acc[p][1] += xv * wv0.y;
                        acc[p][2] += xv * wv0.z;
                        acc[p][3] += xv * wv0.w;
                        acc[p][4] += xv * wv1.x;
                        acc[p][5] += xv * wv1.y;
                        acc[p][6] += xv * wv1.z;
                        acc[p][7] += xv * wv1.w;
                    }
                }
            }
        }

        #pragma unroll
        for (int p = 0; p < PCH; ++p) {
            float* po = ob + ((size_t)(r0 + p) * WI_ + w) * COUT;
            *(float4*)(po)     = make_float4(acc[p][0], acc[p][1], acc[p][2], acc[p][3]);
            *(float4*)(po + 4) = make_float4(acc[p][4], acc[p][5], acc[p][6], acc[p][7]);
        }
    }
}

extern "C" void kernel_launch(void* const* d_in, const int* in_sizes, int n_in,
                              void* d_out, int out_size, void* d_ws, size_t ws_size,
                              hipStream_t stream) {
    const float* X    = (const float*)d_in[0];
    const float* Wt   = (const float*)d_in[1];
    const float* bias = (const float*)d_in[2];
    const float* Werr = (const float*)d_in[3];
    const float* Berr = (const float*)d_in[4];
    float* out = (float*)d_out;

    dim3 grid(H_ / TH, B_);
    conv_aconnect_kernel<<<grid, 256, 0, stream>>>(X, Wt, bias, Werr, Berr, out);
}

// Round 3
// 504.792 us; speedup vs baseline: 5.1043x; 5.0725x over previous
//
#include <hip/hip_runtime.h>

#define B_    128
#define H_    256
#define WI_   256
#define CIN   8
#define COUT  8
#define CT    32      // output columns per block
#define SS    64      // output rows per block strip

// thread = (one output column) x (one cout). 256 threads = 32 cols x 8 couts.
// Rolling 3-row accumulator: input row r contributes kh=0 -> out r+1,
// kh=1 -> out r, kh=2 -> out r-1 (which then completes and is stored).

__global__ __launch_bounds__(256, 3)
void conv_aconnect_kernel(const float* __restrict__ X,
                          const float* __restrict__ Wt,
                          const float* __restrict__ bias,
                          const float* __restrict__ Werr,
                          const float* __restrict__ Berr,
                          float* __restrict__ out)
{
    const int tid  = threadIdx.x;
    const int o    = tid & 7;            // cout
    const int cl   = tid >> 3;           // local column 0..31
    const int colg = blockIdx.x * CT + cl;
    const int rs   = blockIdx.y * SS;
    const int b    = blockIdx.z;

    // ---- per-thread noisy weights into registers (72 floats) ----
    float w[3][3][CIN];
    {
        const float* we = Werr + (size_t)b * (3*3*CIN*COUT);
        #pragma unroll
        for (int kh = 0; kh < 3; ++kh)
            #pragma unroll
            for (int kw = 0; kw < 3; ++kw)
                #pragma unroll
                for (int ci = 0; ci < CIN; ++ci) {
                    const int idx = ((kh*3 + kw)*CIN + ci)*COUT + o;
                    w[kh][kw][ci] = Wt[idx] * we[idx];
                }
    }
    // image-edge columns: clamp the halo pointer, zero the matching weights
    if (colg == 0) {
        #pragma unroll
        for (int kh = 0; kh < 3; ++kh)
            #pragma unroll
            for (int ci = 0; ci < CIN; ++ci) w[kh][0][ci] = 0.f;
    }
    if (colg == WI_ - 1) {
        #pragma unroll
        for (int kh = 0; kh < 3; ++kh)
            #pragma unroll
            for (int ci = 0; ci < CIN; ++ci) w[kh][2][ci] = 0.f;
    }

    const float biasv = bias[o] * Berr[(size_t)b * COUT + o];

    const float* xb = X + (size_t)b * H_ * WI_ * CIN;
    const int cLc = (colg > 0)       ? colg - 1 : 0;
    const int cRc = (colg < WI_ - 1) ? colg + 1 : WI_ - 1;
    const float* pL = xb + (size_t)cLc  * CIN;
    const float* pC = xb + (size_t)colg * CIN;
    const float* pR = xb + (size_t)cRc  * CIN;
    float* po = out + ((size_t)b * H_ * WI_ + colg) * COUT + o;

    float accA = 0.f, accB = 0.f, accC = 0.f;
    int rr = rs - 1;

#define STEP(A, B, C) do {                                                   \
    float xr[3][CIN];                                                        \
    if ((unsigned)rr < (unsigned)H_) {                                       \
        const size_t ro = (size_t)rr * (WI_ * CIN);                          \
        const float4 v0 = *(const float4*)(pL + ro);                         \
        const float4 v1 = *(const float4*)(pL + ro + 4);                     \
        const float4 v2 = *(const float4*)(pC + ro);                         \
        const float4 v3 = *(const float4*)(pC + ro + 4);                     \
        const float4 v4 = *(const float4*)(pR + ro);                         \
        const float4 v5 = *(const float4*)(pR + ro + 4);                     \
        xr[0][0]=v0.x; xr[0][1]=v0.y; xr[0][2]=v0.z; xr[0][3]=v0.w;          \
        xr[0][4]=v1.x; xr[0][5]=v1.y; xr[0][6]=v1.z; xr[0][7]=v1.w;          \
        xr[1][0]=v2.x; xr[1][1]=v2.y; xr[1][2]=v2.z; xr[1][3]=v2.w;          \
        xr[1][4]=v3.x; xr[1][5]=v3.y; xr[1][6]=v3.z; xr[1][7]=v3.w;          \
        xr[2][0]=v4.x; xr[2][1]=v4.y; xr[2][2]=v4.z; xr[2][3]=v4.w;          \
        xr[2][4]=v5.x; xr[2][5]=v5.y; xr[2][6]=v5.z; xr[2][7]=v5.w;          \
    } else {                                                                 \
        _Pragma("unroll")                                                    \
        for (int kk = 0; kk < 3; ++kk) {                                     \
            _Pragma("unroll")                                                \
            for (int ci = 0; ci < CIN; ++ci) xr[kk][ci] = 0.f;               \
        }                                                                    \
    }                                                                        \
    C = 0.f;                                                                 \
    _Pragma("unroll")                                                        \
    for (int kw = 0; kw < 3; ++kw) {                                         \
        _Pragma("unroll")                                                    \
        for (int ci = 0; ci < CIN; ++ci) {                                   \
            const float xv = xr[kw][ci];                                     \
            A += xv * w[2][kw][ci];                                          \
            B += xv * w[1][kw][ci];                                          \
            C += xv * w[0][kw][ci];                                          \
        }                                                                    \
    }                                                                        \
    {                                                                        \
        const int q = rr - 1;                                                \
        if (q >= rs && q < rs + SS)                                          \
            po[(size_t)q * (WI_ * COUT)] = A + biasv;                        \
    }                                                                        \
    ++rr;                                                                    \
} while (0)

    // (SS + 2) = 66 input-row steps, rotation period 3 -> 22 iterations
    #pragma unroll 1
    for (int it = 0; it < (SS + 2) / 3; ++it) {
        STEP(accA, accB, accC);
        STEP(accB, accC, accA);
        STEP(accC, accA, accB);
    }
#undef STEP
}

extern "C" void kernel_launch(void* const* d_in, const int* in_sizes, int n_in,
                              void* d_out, int out_size, void* d_ws, size_t ws_size,
                              hipStream_t stream) {
    const float* X    = (const float*)d_in[0];
    const float* Wt   = (const float*)d_in[1];
    const float* bias = (const float*)d_in[2];
    const float* Werr = (const float*)d_in[3];
    const float* Berr = (const float*)d_in[4];
    float* out = (float*)d_out;

    dim3 grid(WI_ / CT, H_ / SS, B_);
    conv_aconnect_kernel<<<grid, 256, 0, stream>>>(X, Wt, bias, Werr, Berr, out);
}

// Round 4
// 337.562 us; speedup vs baseline: 7.6329x; 1.4954x over previous
//
#include <hip/hip_runtime.h>

#define B_    128
#define H_    256
#define WI_   256
#define CIN   8
#define COUT  8
#define CT    32      // output columns per block (x 8 couts = 256 threads)
#define SS    64      // output rows per block
#define RST   (WI_*CIN)    // 2048 floats per input row
#define OST   (WI_*COUT)   // 2048 floats per output row

// thread = (column, cout). Rolling 3-accumulator over input rows:
// input row r contributes w[2]->out r-1 (completes), w[1]->out r, w[0]->out r+1.
// Steady loop has NO branches (peeled first/last rows) so loads pipeline.

__global__ __launch_bounds__(256, 3)
void conv_aconnect_kernel(const float* __restrict__ X,
                          const float* __restrict__ Wt,
                          const float* __restrict__ bias,
                          const float* __restrict__ Werr,
                          const float* __restrict__ Berr,
                          float* __restrict__ out)
{
    const int tid  = threadIdx.x;
    const int o    = tid & 7;            // cout
    const int cl   = tid >> 3;           // local column
    const int colg = blockIdx.x * CT + cl;
    const int rs   = blockIdx.y * SS;
    const int b    = blockIdx.z;

    // per-thread noisy weights (72 regs), loop-invariant
    float w[3][3][CIN];
    {
        const float* we = Werr + (size_t)b * 576;
        #pragma unroll
        for (int kh = 0; kh < 3; ++kh)
            #pragma unroll
            for (int kw = 0; kw < 3; ++kw)
                #pragma unroll
                for (int ci = 0; ci < CIN; ++ci) {
                    const int idx = ((kh*3 + kw)*CIN + ci)*COUT + o;
                    w[kh][kw][ci] = Wt[idx] * we[idx];
                }
    }
    // image-edge columns: clamp halo pointer, zero the matching weights
    if (colg == 0) {
        #pragma unroll
        for (int kh = 0; kh < 3; ++kh)
            #pragma unroll
            for (int ci = 0; ci < CIN; ++ci) w[kh][0][ci] = 0.f;
    }
    if (colg == WI_ - 1) {
        #pragma unroll
        for (int kh = 0; kh < 3; ++kh)
            #pragma unroll
            for (int ci = 0; ci < CIN; ++ci) w[kh][2][ci] = 0.f;
    }
    const float biasv = bias[o] * Berr[(size_t)b * COUT + o];

    const float* xb = X + (size_t)b * H_ * RST;
    const int cL = (colg > 0)       ? colg - 1 : 0;
    const int cR = (colg < WI_ - 1) ? colg + 1 : WI_ - 1;
    const float* pL = xb + (ptrdiff_t)cL   * CIN + (ptrdiff_t)(rs - 1) * RST;
    const float* pC = xb + (ptrdiff_t)colg * CIN + (ptrdiff_t)(rs - 1) * RST;
    const float* pR = xb + (ptrdiff_t)cR   * CIN + (ptrdiff_t)(rs - 1) * RST;
    float* ps = out + ((size_t)(b * H_ + rs) * WI_ + colg) * COUT + o;

    float A = 0.f, Bv = 0.f, Cv = 0.f;

#define STEP(P2, P1, P0, DOSTORE) do {                                   \
    float xr[3][CIN];                                                    \
    {                                                                    \
        const float4 v0 = *(const float4*)(pL);                          \
        const float4 v1 = *(const float4*)(pL + 4);                      \
        const float4 v2 = *(const float4*)(pC);                          \
        const float4 v3 = *(const float4*)(pC + 4);                      \
        const float4 v4 = *(const float4*)(pR);                          \
        const float4 v5 = *(const float4*)(pR + 4);                      \
        xr[0][0]=v0.x; xr[0][1]=v0.y; xr[0][2]=v0.z; xr[0][3]=v0.w;      \
        xr[0][4]=v1.x; xr[0][5]=v1.y; xr[0][6]=v1.z; xr[0][7]=v1.w;      \
        xr[1][0]=v2.x; xr[1][1]=v2.y; xr[1][2]=v2.z; xr[1][3]=v2.w;      \
        xr[1][4]=v3.x; xr[1][5]=v3.y; xr[1][6]=v3.z; xr[1][7]=v3.w;      \
        xr[2][0]=v4.x; xr[2][1]=v4.y; xr[2][2]=v4.z; xr[2][3]=v4.w;      \
        xr[2][4]=v5.x; xr[2][5]=v5.y; xr[2][6]=v5.z; xr[2][7]=v5.w;      \
    }                                                                    \
    P0 = 0.f;                                                            \
    _Pragma("unroll")                                                    \
    for (int kw = 0; kw < 3; ++kw) {                                     \
        _Pragma("unroll")                                                \
        for (int ci = 0; ci < CIN; ++ci) {                               \
            const float xv = xr[kw][ci];                                 \
            P2 += xv * w[2][kw][ci];                                     \
            P1 += xv * w[1][kw][ci];                                     \
            P0 += xv * w[0][kw][ci];                                     \
        }                                                                \
    }                                                                    \
    if (DOSTORE) { *ps = P2 + biasv; ps += OST; }                        \
    pL += RST; pC += RST; pR += RST;                                     \
} while (0)

    if (rs > 0) {
        STEP(A, Bv, Cv, 0);                 // input row rs-1 (real)
    } else {
        pL += RST; pC += RST; pR += RST;    // zero-pad row: contributes 0
    }
    STEP(Bv, Cv, A, 0);                     // input row rs

    #pragma unroll 1
    for (int it = 0; it < 21; ++it) {       // input rows rs+1 .. rs+63
        STEP(Cv, A, Bv, 1);                 // stores out rs+3*it
        STEP(A, Bv, Cv, 1);
        STEP(Bv, Cv, A, 1);
    }
    // out rows rs..rs+62 stored; out rs+63 needs input row rs+64
    if (rs + SS < H_) {
        STEP(Cv, A, Bv, 1);                 // input row rs+64 -> store out rs+63
    } else {
        *ps = Cv + biasv;                   // bottom strip: padded row adds 0
    }
#undef STEP
}

extern "C" void kernel_launch(void* const* d_in, const int* in_sizes, int n_in,
                              void* d_out, int out_size, void* d_ws, size_t ws_size,
                              hipStream_t stream) {
    const float* X    = (const float*)d_in[0];
    const float* Wt   = (const float*)d_in[1];
    const float* bias = (const float*)d_in[2];
    const float* Werr = (const float*)d_in[3];
    const float* Berr = (const float*)d_in[4];
    float* out = (float*)d_out;

    dim3 grid(WI_ / CT, H_ / SS, B_);
    conv_aconnect_kernel<<<grid, 256, 0, stream>>>(X, Wt, bias, Werr, Berr, out);
}